// Round 12
// baseline (380.257 us; speedup 1.0000x reference)
//
#include <hip/hip_runtime.h>
#include <hip/hip_bf16.h>

#define NN 60000
#define NE 600000
#define DD 128
#define NTOT (NE + NN)
#define NB ((NN + 255) / 256)       // 235 blocks for scan
#define NBK1 ((NN + 63) / 64)       // 938 blocks for gemm / bnstat
#define DEGB ((NE + 255) / 256)     // 2344 deg blocks
#define GGRID ((NN + 3) / 4)        // 15000 gather blocks (4 nodes each)
#define RED1 32                     // bnredA blocks
#define NBUCK 235                   // dst>>8 buckets
#define SUBB 8                      // sub-buckets (by blockIdx&7 ~ XCD)
#define BCAP 1024                   // records per sub-bucket (mean 322, +39 sigma)
// gemmfill interleave: 1408 = 469*3 + 1; per 3 = 2 gemm + 1 fill; fill ids 0..469
#define GF2_TOT 1408
#define GF2_FULL 1407

typedef __attribute__((ext_vector_type(8))) short short8;
typedef __attribute__((ext_vector_type(4))) float f32x4;

__device__ __forceinline__ unsigned short f2bf(float f) {
    unsigned int u = __float_as_uint(f);
    unsigned int r = (u + 0x7FFF + ((u >> 16) & 1)) >> 16;  // RNE
    return (unsigned short)r;
}
__device__ __forceinline__ float bflo(unsigned int u) { return __uint_as_float(u << 16); }
__device__ __forceinline__ float bfhi(unsigned int u) { return __uint_as_float(u & 0xFFFF0000u); }

// ---- deg + bucket scatter (blocks < DEGB) fused with W convert (blocks >= DEGB) ----
// Radix pass 1: append {src|dst<<16, rank} to sub-bucket fronts (sequential line fills).
__global__ __launch_bounds__(256) void degw_kernel(const int* __restrict__ src, const int* __restrict__ dst,
                                                   int* __restrict__ deg, int* __restrict__ bcur,
                                                   uint2* __restrict__ bucket,
                                                   const float* __restrict__ W0, const float* __restrict__ W1,
                                                   const float* __restrict__ W2, unsigned short* __restrict__ Wsw) {
    if (blockIdx.x < DEGB) {
        int e = blockIdx.x * 256 + threadIdx.x;
        if (e < NE) {
            int t = dst[e];
            int rk = atomicAdd(&deg[t], 1);
            int b8 = (t >> 8) * SUBB + (blockIdx.x & (SUBB - 1));
            int pos = atomicAdd(&bcur[b8], 1);
            if (pos < BCAP) {
                uint2 rec;
                rec.x = (unsigned int)src[e] | ((unsigned int)t << 16);
                rec.y = (unsigned int)rk;
                bucket[(size_t)b8 * BCAP + pos] = rec;
            }
        }
    } else {
        int idx = (blockIdx.x - DEGB) * 256 + threadIdx.x;  // 3 * 32 frags * 64 lanes = 6144
        if (idx >= 3 * 32 * 64) return;
        int L = idx >> 11;
        int rem = idx & 2047;
        int frag = rem >> 6;         // 0..31  (kc*8 + nt)
        int lane = rem & 63;
        int kc = frag >> 3, nt = frag & 7;
        int m = lane & 15, q = lane >> 4;
        int n = nt * 16 + m;
        int k0 = kc * 32 + q * 8;
        const float* W = (L == 0) ? W0 : (L == 1) ? W1 : W2;
        unsigned int p[4];
#pragma unroll
        for (int j = 0; j < 4; j++) {
            unsigned int b0 = f2bf(W[(size_t)(k0 + 2 * j) * DD + n]);
            unsigned int b1 = f2bf(W[(size_t)(k0 + 2 * j + 1) * DD + n]);
            p[j] = b0 | (b1 << 16);
        }
        uint4 o; o.x = p[0]; o.y = p[1]; o.z = p[2]; o.w = p[3];
        *(uint4*)(Wsw + ((size_t)L * 2048 + (size_t)frag * 64 + lane) * 8) = o;
    }
}

// ---- scanA: per-block sums of (deg+1), fused dinv (baseline verbatim) ----
__global__ __launch_bounds__(256) void scanA_kernel(const int* __restrict__ deg, int* __restrict__ partials,
                                                    float* __restrict__ dinv) {
    __shared__ int lds[256];
    int i = blockIdx.x * 256 + threadIdx.x;
    int dv = (i < NN) ? deg[i] : 0;
    if (i < NN) dinv[i] = rsqrtf((float)(dv + 1));
    int v = (i < NN) ? dv + 1 : 0;
    lds[threadIdx.x] = v;
    __syncthreads();
    for (int off = 128; off > 0; off >>= 1) {
        if (threadIdx.x < off) lds[threadIdx.x] += lds[threadIdx.x + off];
        __syncthreads();
    }
    if (threadIdx.x == 0) partials[blockIdx.x] = lds[0];
}

// ---- scanC with inlined scanB: each block computes its own blockoff (sum of partials[0..bid)) ----
__global__ __launch_bounds__(256) void scanC_kernel(const int* __restrict__ deg,
                                                    const int* __restrict__ partials,
                                                    int* __restrict__ rowptr) {
    __shared__ int lds[256];
    __shared__ int lds2[256];
    int i = blockIdx.x * 256 + threadIdx.x;
    int t = threadIdx.x;
    // blockoff = sum of partials[0..blockIdx.x)
    lds2[t] = (t < (int)blockIdx.x) ? partials[t] : 0;   // bid <= 234 < 256 so t<bid => valid
    __syncthreads();
    for (int off = 128; off > 0; off >>= 1) {
        if (t < off) lds2[t] += lds2[t + off];
        __syncthreads();
    }
    int blockoff = lds2[0];
    // local exclusive prefix of deg+1 (Hillis-Steele)
    int v = (i < NN) ? deg[i] + 1 : 0;
    lds[t] = v;
    __syncthreads();
    for (int off = 1; off < 256; off <<= 1) {
        int u = (t >= off) ? lds[t - off] : 0;
        __syncthreads();
        lds[t] += u;
        __syncthreads();
    }
    if (i < NN) rowptr[i] = blockoff + lds[t] - v;
    if (blockIdx.x == 0 && t == 0) rowptr[NN] = NTOT;
}

// ---- radix fill pass 2: bucket blocks (id<NBUCK) write csr locally; self-loop blocks follow ----
__device__ __forceinline__ void fill_body(int fid,
                                          const int* __restrict__ bcur, const uint2* __restrict__ bucket,
                                          const int* __restrict__ rowptr, const int* __restrict__ deg,
                                          const float* __restrict__ dinv, unsigned int* __restrict__ csr) {
    if (fid < NBUCK) {
        // bucket fid: final csr targets span ~11 KB (L2-local to this block)
#pragma unroll 1
        for (int sb = 0; sb < SUBB; sb++) {
            int b8 = fid * SUBB + sb;
            int cnt = min(bcur[b8], BCAP);
            const uint2* list = bucket + (size_t)b8 * BCAP;
            for (int i = threadIdx.x; i < cnt; i += 256) {
                uint2 rec = list[i];
                int s = rec.x & 0xFFFF;
                int t = rec.x >> 16;
                csr[rowptr[t] + (int)rec.y] =
                    (unsigned int)s | ((unsigned int)f2bf(dinv[s] * dinv[t]) << 16);
            }
        }
    } else {
        // self-loops: node t's record at rowptr[t]+deg[t] (writes naturally ordered)
        int t = (fid - NBUCK) * 256 + threadIdx.x;
        if (t < NN)
            csr[rowptr[t] + deg[t]] =
                (unsigned int)t | ((unsigned int)f2bf(dinv[t] * dinv[t]) << 16);
    }
}

// ---- MFMA GEMM body (R7/R9/R11 verbatim: bf16 output). BF16IN=true computes normp inline. ----
template <bool BF16IN>
__device__ __forceinline__ void gemm_body(int bid, const void* __restrict__ Ain,
                                          const unsigned short* __restrict__ Wsw,
                                          const float* __restrict__ bnp2,
                                          const float* __restrict__ gg,
                                          const float* __restrict__ bb,
                                          unsigned short* __restrict__ C) {
    __shared__ unsigned short Atile[64 * 128];  // 16 KB, swizzled 16B chunks
    __shared__ float rep[4][16][68];            // 17.4 KB, per-wave repack
    __shared__ float normp[256];                // 1 KB scale/shift
    int tid = threadIdx.x;
    int wslot = tid >> 6;
    int l = tid & 63;
    int m = l & 15;
    int q = l >> 4;
    int rblk = bid * 64;

    if (BF16IN) {
        float tot = 0.f;
#pragma unroll 8
        for (int r = 0; r < RED1; r++) tot += bnp2[(size_t)r * 256 + tid];
        normp[tid] = tot;
        __syncthreads();
        if (tid < 128) {
            float sm = normp[tid], sq = normp[128 + tid];
            const float invN = 1.0f / (float)NN;
            float mu = sm * invN;
            float var = sq * invN - mu * mu;
            float sc = rsqrtf(var + 1e-5f) * gg[tid];
            normp[tid] = sc;
            normp[128 + tid] = bb[tid] - mu * sc;
        }
        __syncthreads();
    }

#pragma unroll
    for (int p = 0; p < 4; p++) {
        int rowl = p * 16 + (tid >> 4);
        int c = tid & 15;
        int row = min(rblk + rowl, NN - 1);
        float a[8];
        if (BF16IN) {
            uint4 u = *(const uint4*)((const unsigned short*)Ain + (size_t)row * DD + c * 8);
            a[0] = bflo(u.x); a[1] = bfhi(u.x); a[2] = bflo(u.y); a[3] = bfhi(u.y);
            a[4] = bflo(u.z); a[5] = bfhi(u.z); a[6] = bflo(u.w); a[7] = bfhi(u.w);
#pragma unroll
            for (int j = 0; j < 8; j++) {
                float v = fmaf(a[j], normp[c * 8 + j], normp[128 + c * 8 + j]);
                a[j] = (v >= 0.f) ? v : 0.01f * v;
            }
        } else {
            const float* Af = (const float*)Ain + (size_t)row * DD + c * 8;
            float4 x0 = *(const float4*)Af;
            float4 x1 = *(const float4*)(Af + 4);
            a[0] = x0.x; a[1] = x0.y; a[2] = x0.z; a[3] = x0.w;
            a[4] = x1.x; a[5] = x1.y; a[6] = x1.z; a[7] = x1.w;
        }
        unsigned int w0 = f2bf(a[0]) | ((unsigned int)f2bf(a[1]) << 16);
        unsigned int w1 = f2bf(a[2]) | ((unsigned int)f2bf(a[3]) << 16);
        unsigned int w2 = f2bf(a[4]) | ((unsigned int)f2bf(a[5]) << 16);
        unsigned int w3 = f2bf(a[6]) | ((unsigned int)f2bf(a[7]) << 16);
        uint4 wv; wv.x = w0; wv.y = w1; wv.z = w2; wv.w = w3;
        *(uint4*)&Atile[rowl * 128 + ((c ^ (rowl & 15)) * 8)] = wv;
    }
    __syncthreads();

    f32x4 acc[8];
#pragma unroll
    for (int i = 0; i < 8; i++) acc[i] = (f32x4){0.f, 0.f, 0.f, 0.f};
    int rowl_w = wslot * 16 + m;
#pragma unroll
    for (int kc = 0; kc < 4; kc++) {
        short8 af = *(const short8*)&Atile[rowl_w * 128 + (((kc * 4 + q) ^ m) * 8)];
#pragma unroll
        for (int nt = 0; nt < 8; nt++) {
            short8 bf = *(const short8*)(Wsw + ((size_t)(kc * 8 + nt) * 64 + l) * 8);
            acc[nt] = __builtin_amdgcn_mfma_f32_16x16x32_bf16(af, bf, acc[nt], 0, 0, 0);
        }
    }

    int wrow0 = rblk + wslot * 16;
    int r2 = l >> 2, c2 = l & 3;
#pragma unroll
    for (int pass = 0; pass < 2; pass++) {
#pragma unroll
        for (int ntl = 0; ntl < 4; ntl++) {
            f32x4 a = acc[pass * 4 + ntl];
#pragma unroll
            for (int r = 0; r < 4; r++)
                rep[wslot][q * 4 + r][ntl * 16 + m] = a[r];
        }
        const float* tr = &rep[wslot][r2][c2 * 16];
        float4 v0 = *(const float4*)(tr);
        float4 v1 = *(const float4*)(tr + 4);
        float4 v2 = *(const float4*)(tr + 8);
        float4 v3 = *(const float4*)(tr + 12);
        uint4 oA, oB;
        oA.x = f2bf(v0.x) | ((unsigned int)f2bf(v0.y) << 16);
        oA.y = f2bf(v0.z) | ((unsigned int)f2bf(v0.w) << 16);
        oA.z = f2bf(v1.x) | ((unsigned int)f2bf(v1.y) << 16);
        oA.w = f2bf(v1.z) | ((unsigned int)f2bf(v1.w) << 16);
        oB.x = f2bf(v2.x) | ((unsigned int)f2bf(v2.y) << 16);
        oB.y = f2bf(v2.z) | ((unsigned int)f2bf(v2.w) << 16);
        oB.z = f2bf(v3.x) | ((unsigned int)f2bf(v3.y) << 16);
        oB.w = f2bf(v3.z) | ((unsigned int)f2bf(v3.w) << 16);
        int row = wrow0 + r2;
        if (row < NN) {
            unsigned short* cp = C + (size_t)row * DD + pass * 64 + c2 * 16;
            *(uint4*)cp = oA;
            *(uint4*)(cp + 8) = oB;
        }
    }
}

// ---- gemm L0 || radix-fill pass 2, INTERLEAVED: groups of 3 = 2 gemm + 1 fill ----
__global__ __launch_bounds__(256) void gemmfill_kernel(const float* __restrict__ x,
                                                       const unsigned short* __restrict__ Wsw,
                                                       unsigned short* __restrict__ C,
                                                       const int* __restrict__ bcur, const uint2* __restrict__ bucket,
                                                       const int* __restrict__ rowptr, const int* __restrict__ deg,
                                                       const float* __restrict__ dinv, unsigned int* __restrict__ csr) {
    int bid = blockIdx.x;
    bool isg;
    int id;
    if (bid < GF2_FULL) {
        int grp = bid / 3, r = bid - grp * 3;
        if (r < 2) { isg = true;  id = grp * 2 + r; }   // 0..937
        else       { isg = false; id = grp; }           // 0..468
    } else {
        isg = false; id = 469;                          // last fill block
    }
    if (isg)
        gemm_body<false>(id, x, Wsw, nullptr, nullptr, nullptr, C);
    else
        fill_body(id, bcur, bucket, rowptr, deg, dinv, csr);
}

__global__ __launch_bounds__(256) void gemm_bf16_kernel(const unsigned short* __restrict__ Ain,
                                                        const unsigned short* __restrict__ Wsw,
                                                        const float* __restrict__ bnp2,
                                                        const float* __restrict__ g,
                                                        const float* __restrict__ be,
                                                        unsigned short* __restrict__ C) {
    gemm_body<true>(blockIdx.x, Ain, Wsw, bnp2, g, be, C);
}

// ---- CSR gather: R9/R11 verbatim (quarter-wave, no epilogue, no barrier) ----
__global__ __launch_bounds__(256) void gather_kernel(const unsigned short* __restrict__ xw,
                                                     const int* __restrict__ rowptr,
                                                     const unsigned int* __restrict__ csr,
                                                     unsigned short* __restrict__ agg) {
    int wid = (int)((blockIdx.x * 256 + threadIdx.x) >> 6);
    int l = threadIdx.x & 63;
    if (wid >= NN) return;
    int beg = rowptr[wid], end = rowptr[wid + 1];
    int q = l >> 4;          // quarter-wave: edge slot 0..3
    int fb = (l & 15) * 8;   // first feature of this lane's 16B chunk
    float a0 = 0.f, a1 = 0.f, a2 = 0.f, a3 = 0.f, a4 = 0.f, a5 = 0.f, a6 = 0.f, a7 = 0.f;
    for (int base = beg; base < end; base += 64) {
        int nrec = min(end - base, 64);
        unsigned int myrec = csr[base + min(l, nrec - 1)];  // all records for this chunk, one load
        int i = 0;
        for (; i + 8 <= nrec; i += 8) {
            unsigned int r0 = __shfl(myrec, i + q);
            unsigned int r1 = __shfl(myrec, i + 4 + q);
            uint4 u0 = *(const uint4*)(xw + (size_t)(r0 & 0xFFFFu) * DD + fb);
            uint4 u1 = *(const uint4*)(xw + (size_t)(r1 & 0xFFFFu) * DD + fb);
            float c0 = bfhi(r0), c1 = bfhi(r1);
            a0 += bflo(u0.x) * c0; a1 += bfhi(u0.x) * c0;
            a2 += bflo(u0.y) * c0; a3 += bfhi(u0.y) * c0;
            a4 += bflo(u0.z) * c0; a5 += bfhi(u0.z) * c0;
            a6 += bflo(u0.w) * c0; a7 += bfhi(u0.w) * c0;
            a0 += bflo(u1.x) * c1; a1 += bfhi(u1.x) * c1;
            a2 += bflo(u1.y) * c1; a3 += bfhi(u1.y) * c1;
            a4 += bflo(u1.z) * c1; a5 += bfhi(u1.z) * c1;
            a6 += bflo(u1.w) * c1; a7 += bfhi(u1.w) * c1;
        }
        for (; i < nrec; i += 4) {
            int e = i + q;
            unsigned int r = __shfl(myrec, min(e, nrec - 1));
            float c = (e < nrec) ? bfhi(r) : 0.f;   // dummy lanes hit a hot line, coef 0
            uint4 u = *(const uint4*)(xw + (size_t)(r & 0xFFFFu) * DD + fb);
            a0 += bflo(u.x) * c; a1 += bfhi(u.x) * c;
            a2 += bflo(u.y) * c; a3 += bfhi(u.y) * c;
            a4 += bflo(u.z) * c; a5 += bfhi(u.z) * c;
            a6 += bflo(u.w) * c; a7 += bfhi(u.w) * c;
        }
    }
    a0 += __shfl_xor(a0, 16); a0 += __shfl_xor(a0, 32);
    a1 += __shfl_xor(a1, 16); a1 += __shfl_xor(a1, 32);
    a2 += __shfl_xor(a2, 16); a2 += __shfl_xor(a2, 32);
    a3 += __shfl_xor(a3, 16); a3 += __shfl_xor(a3, 32);
    a4 += __shfl_xor(a4, 16); a4 += __shfl_xor(a4, 32);
    a5 += __shfl_xor(a5, 16); a5 += __shfl_xor(a5, 32);
    a6 += __shfl_xor(a6, 16); a6 += __shfl_xor(a6, 32);
    a7 += __shfl_xor(a7, 16); a7 += __shfl_xor(a7, 32);
    if (q == 0) {
        uint4 o;
        o.x = (unsigned int)f2bf(a0) | ((unsigned int)f2bf(a1) << 16);
        o.y = (unsigned int)f2bf(a2) | ((unsigned int)f2bf(a3) << 16);
        o.z = (unsigned int)f2bf(a4) | ((unsigned int)f2bf(a5) << 16);
        o.w = (unsigned int)f2bf(a6) | ((unsigned int)f2bf(a7) << 16);
        *(uint4*)(agg + (size_t)wid * DD + fb) = o;
    }
}

// ---- BN stats stage 1 (baseline verbatim): per-block partials, grid 938 ----
__global__ __launch_bounds__(256) void bnstat1_kernel(const unsigned short* __restrict__ h,
                                                      float* __restrict__ partials) {
    int t = threadIdx.x;
    int rg = t >> 4;       // row group 0..15
    int c  = t & 15;       // feature chunk: features 8c..8c+7
    int rbase = blockIdx.x * 64;
    float s[8], q[8];
#pragma unroll
    for (int j = 0; j < 8; j++) { s[j] = 0.f; q[j] = 0.f; }
#pragma unroll
    for (int p = 0; p < 4; p++) {
        int row = rbase + rg + 16 * p;
        if (row < NN) {
            uint4 u = *(const uint4*)(h + (size_t)row * DD + c * 8);
            float v;
            v = bflo(u.x); s[0] += v; q[0] += v * v;
            v = bfhi(u.x); s[1] += v; q[1] += v * v;
            v = bflo(u.y); s[2] += v; q[2] += v * v;
            v = bfhi(u.y); s[3] += v; q[3] += v * v;
            v = bflo(u.z); s[4] += v; q[4] += v * v;
            v = bfhi(u.z); s[5] += v; q[5] += v * v;
            v = bflo(u.w); s[6] += v; q[6] += v * v;
            v = bfhi(u.w); s[7] += v; q[7] += v * v;
        }
    }
    __shared__ float lds[2][16][128];  // 16 KB
#pragma unroll
    for (int j = 0; j < 8; j++) {
        lds[0][rg][c * 8 + j] = s[j];
        lds[1][rg][c * 8 + j] = q[j];
    }
    __syncthreads();
    int f = t & 127, stat = t >> 7;
    float acc = 0.f;
#pragma unroll
    for (int r = 0; r < 16; r++) acc += lds[stat][r][f];
    partials[(size_t)blockIdx.x * 256 + stat * 128 + f] = acc;  // coalesced 1KB row
}

// ---- BN reduce stage A (baseline verbatim): 32 blocks each sum ~29 of 938 rows ----
__global__ __launch_bounds__(256) void bnredA_kernel(const float* __restrict__ partials,
                                                     float* __restrict__ p2) {
    int t = threadIdx.x;
    int b = blockIdx.x;  // 0..RED1-1
    float acc = 0.f;
#pragma unroll 4
    for (int r = b; r < NBK1; r += RED1)
        acc += partials[(size_t)r * 256 + t];   // coalesced, independent
    p2[(size_t)b * 256 + t] = acc;
}

// ---- final: out = bf16(agg)*scale+shift, inline finalize. Grid 938. ----
__global__ __launch_bounds__(256) void bnapply_kernel(const unsigned short* __restrict__ h,
                                                      const float* __restrict__ bnp2,
                                                      const float* __restrict__ g,
                                                      const float* __restrict__ be,
                                                      float* __restrict__ out) {
    __shared__ float normp[256];
    int t = threadIdx.x;
    float tot = 0.f;
#pragma unroll 8
    for (int r = 0; r < RED1; r++) tot += bnp2[(size_t)r * 256 + t];
    normp[t] = tot;
    __syncthreads();
    if (t < 128) {
        float sm = normp[t], sq = normp[128 + t];
        const float invN = 1.0f / (float)NN;
        float mu = sm * invN;
        float var = sq * invN - mu * mu;
        float sc = rsqrtf(var + 1e-5f) * g[t];
        normp[t] = sc;
        normp[128 + t] = be[t] - mu * sc;
    }
    __syncthreads();
#pragma unroll
    for (int k = 0; k < 8; k++) {
        int idx = blockIdx.x * 2048 + k * 256 + t;
        if (idx < NN * DD / 4) {
            int d = (idx * 4) & 127;
            uint2 u = *(const uint2*)(h + (size_t)idx * 4);
            float4 sc = *(const float4*)&normp[d];
            float4 sh = *(const float4*)&normp[128 + d];
            float4 o;
            o.x = fmaf(bflo(u.x), sc.x, sh.x);
            o.y = fmaf(bfhi(u.x), sc.y, sh.y);
            o.z = fmaf(bflo(u.y), sc.z, sh.z);
            o.w = fmaf(bfhi(u.y), sc.w, sh.w);
            *(float4*)&out[(size_t)idx * 4] = o;
        }
    }
}

extern "C" void kernel_launch(void* const* d_in, const int* in_sizes, int n_in,
                              void* d_out, int out_size, void* d_ws, size_t ws_size,
                              hipStream_t stream) {
    const float* x = (const float*)d_in[0];
    const int* ei = (const int*)d_in[1];
    const int* srcp = ei;
    const int* dstp = ei + NE;
    const float* w[3]  = {(const float*)d_in[2], (const float*)d_in[6],  (const float*)d_in[10]};
    const float* g[3]  = {(const float*)d_in[4], (const float*)d_in[8],  (const float*)d_in[12]};
    const float* be[3] = {(const float*)d_in[5], (const float*)d_in[9],  (const float*)d_in[13]};

    // workspace layout (~56 MB of 256 MB), all chunks 16-B aligned
    unsigned short* xwb  = (unsigned short*)d_ws;        // bf16 xw  [NN*DD]
    unsigned short* aggb = xwb + (size_t)NN * DD;        // bf16 agg [NN*DD]
    // ---- zeroed region (single memset): deg + bcur ----
    int* deg    = (int*)(aggb + (size_t)NN * DD);        // [NN]
    int* bcur   = deg + NN;                              // [NBUCK*SUBB]
    // ---- end zeroed region ----
    int* rowptr = bcur + NBUCK * SUBB;                   // [NN+16]
    float* dinv = (float*)(rowptr + NN + 16);            // [NN]
    int* spart  = (int*)(dinv + NN);                     // [256] scan partials
    float* bnp  = (float*)(spart + 256);                 // [NBK1*256] bn partials (~960 KB)
    float* bnp2 = bnp + (size_t)NBK1 * 256;              // [RED1*256] raw sums
    unsigned short* Wsw = (unsigned short*)(bnp2 + RED1 * 256);  // [3*128*128] bf16
    unsigned int* csr = (unsigned int*)(Wsw + 3 * DD * DD);      // [NTOT] packed {coef_bf16|src16}
    uint2* bucket = (uint2*)(csr + NTOT + 16);           // [NBUCK*SUBB*BCAP] radix records (15.4 MB)
    float* out = (float*)d_out;

    // ---- build: deg+bucket||wcvt -> scanA -> scanC(w/ inlined scanB) -> (gemm L0 || fill p2) ----
    hipMemsetAsync(deg, 0, (size_t)(NN + NBUCK * SUBB) * sizeof(int), stream);
    degw_kernel<<<DEGB + 24, 256, 0, stream>>>(srcp, dstp, deg, bcur, bucket, w[0], w[1], w[2], Wsw);
    scanA_kernel<<<NB, 256, 0, stream>>>(deg, spart, dinv);
    scanC_kernel<<<NB, 256, 0, stream>>>(deg, spart, rowptr);
    gemmfill_kernel<<<GF2_TOT, 256, 0, stream>>>(x, Wsw, xwb, bcur, bucket, rowptr, deg, dinv, csr);

    for (int L = 0; L < 3; ++L) {
        if (L > 0)
            gemm_bf16_kernel<<<NBK1, 256, 0, stream>>>(aggb, Wsw + (size_t)L * DD * DD,
                                                       bnp2, g[L - 1], be[L - 1], xwb);
        gather_kernel<<<GGRID, 256, 0, stream>>>(xwb, rowptr, csr, aggb);
        bnstat1_kernel<<<NBK1, 256, 0, stream>>>(aggb, bnp);
        bnredA_kernel<<<RED1, 256, 0, stream>>>(bnp, bnp2);
    }
    bnapply_kernel<<<NBK1, 256, 0, stream>>>(aggb, bnp2, g[2], be[2], out);
}

// Round 13
// 294.786 us; speedup vs baseline: 1.2899x; 1.2899x over previous
//
#include <hip/hip_runtime.h>
#include <hip/hip_bf16.h>

#define NN 60000
#define NE 600000
#define DD 128
#define NTOT (NE + NN)
#define NB ((NN + 255) / 256)       // 235 blocks for scan
#define NBK1 ((NN + 63) / 64)       // 938 blocks for gemm / bnstat
#define DEGB ((NE + 255) / 256)     // 2344 deg blocks
#define FILLB ((NTOT + 255) / 256)  // 2579 fill blocks
#define GGRID ((NN + 3) / 4)        // 15000 gather blocks (4 nodes each)
#define RED1 32                     // bnredA blocks
// interleave constants for gemmfill: 3517 = 234*15 + 7; each 15 = 4 gemm + 11 fill
#define GF_TOT (NBK1 + FILLB)       // 3517
#define GF_FULL 3510                // 234*15
#define GF_G936 936                 // 234*4
#define GF_F2574 2574               // 234*11

typedef __attribute__((ext_vector_type(8))) short short8;
typedef __attribute__((ext_vector_type(4))) float f32x4;

__device__ __forceinline__ unsigned short f2bf(float f) {
    unsigned int u = __float_as_uint(f);
    unsigned int r = (u + 0x7FFF + ((u >> 16) & 1)) >> 16;  // RNE
    return (unsigned short)r;
}
__device__ __forceinline__ float bflo(unsigned int u) { return __uint_as_float(u << 16); }
__device__ __forceinline__ float bfhi(unsigned int u) { return __uint_as_float(u & 0xFFFF0000u); }

// ---- deg+rank (blocks < DEGB) fused with W convert (blocks >= DEGB) ----
// R11-proven: ONE atomic per edge, rank recorded so fill needs no atomic.
__global__ __launch_bounds__(256) void degw_kernel(const int* __restrict__ dst, int* __restrict__ deg,
                                                   int* __restrict__ rank,
                                                   const float* __restrict__ W0, const float* __restrict__ W1,
                                                   const float* __restrict__ W2, unsigned short* __restrict__ Wsw) {
    if (blockIdx.x < DEGB) {
        int e = blockIdx.x * 256 + threadIdx.x;
        if (e < NE) rank[e] = atomicAdd(&deg[dst[e]], 1);
    } else {
        int idx = (blockIdx.x - DEGB) * 256 + threadIdx.x;  // 3 * 32 frags * 64 lanes = 6144
        if (idx >= 3 * 32 * 64) return;
        int L = idx >> 11;
        int rem = idx & 2047;
        int frag = rem >> 6;         // 0..31  (kc*8 + nt)
        int lane = rem & 63;
        int kc = frag >> 3, nt = frag & 7;
        int m = lane & 15, q = lane >> 4;
        int n = nt * 16 + m;
        int k0 = kc * 32 + q * 8;
        const float* W = (L == 0) ? W0 : (L == 1) ? W1 : W2;
        unsigned int p[4];
#pragma unroll
        for (int j = 0; j < 4; j++) {
            unsigned int b0 = f2bf(W[(size_t)(k0 + 2 * j) * DD + n]);
            unsigned int b1 = f2bf(W[(size_t)(k0 + 2 * j + 1) * DD + n]);
            p[j] = b0 | (b1 << 16);
        }
        uint4 o; o.x = p[0]; o.y = p[1]; o.z = p[2]; o.w = p[3];
        *(uint4*)(Wsw + ((size_t)L * 2048 + (size_t)frag * 64 + lane) * 8) = o;
    }
}

// ---- scanA: per-block sums of (deg+1), fused dinv (baseline verbatim) ----
__global__ __launch_bounds__(256) void scanA_kernel(const int* __restrict__ deg, int* __restrict__ partials,
                                                    float* __restrict__ dinv) {
    __shared__ int lds[256];
    int i = blockIdx.x * 256 + threadIdx.x;
    int dv = (i < NN) ? deg[i] : 0;
    if (i < NN) dinv[i] = rsqrtf((float)(dv + 1));
    int v = (i < NN) ? dv + 1 : 0;
    lds[threadIdx.x] = v;
    __syncthreads();
    for (int off = 128; off > 0; off >>= 1) {
        if (threadIdx.x < off) lds[threadIdx.x] += lds[threadIdx.x + off];
        __syncthreads();
    }
    if (threadIdx.x == 0) partials[blockIdx.x] = lds[0];
}

// ---- scanC with inlined scanB (R12-exonerated): block computes own offset from partials ----
__global__ __launch_bounds__(256) void scanC_kernel(const int* __restrict__ deg,
                                                    const int* __restrict__ partials,
                                                    int* __restrict__ rowptr) {
    __shared__ int lds[256];
    __shared__ int lds2[256];
    int i = blockIdx.x * 256 + threadIdx.x;
    int t = threadIdx.x;
    lds2[t] = (t < (int)blockIdx.x) ? partials[t] : 0;   // bid <= 234 < 256
    __syncthreads();
    for (int off = 128; off > 0; off >>= 1) {
        if (t < off) lds2[t] += lds2[t + off];
        __syncthreads();
    }
    int blockoff = lds2[0];
    int v = (i < NN) ? deg[i] + 1 : 0;
    lds[t] = v;
    __syncthreads();
    for (int off = 1; off < 256; off <<= 1) {
        int u = (t >= off) ? lds[t - off] : 0;
        __syncthreads();
        lds[t] += u;
        __syncthreads();
    }
    if (i < NN) rowptr[i] = blockoff + lds[t] - v;
    if (blockIdx.x == 0 && t == 0) rowptr[NN] = NTOT;
}

// ---- CSR fill body: atomic-free (rank from degw); record {coef_bf16:16 | src:16} ----
__device__ __forceinline__ void fill_body(int bid, const int* __restrict__ src, const int* __restrict__ dst,
                                          const int* __restrict__ rowptr,
                                          const int* __restrict__ rank, const int* __restrict__ deg,
                                          const float* __restrict__ dinv, unsigned int* __restrict__ csr) {
    int e = bid * 256 + (int)threadIdx.x;
    if (e >= NTOT) return;
    int s, t, rk;
    if (e < NE) { s = src[e]; t = dst[e]; rk = rank[e]; }
    else { s = t = e - NE; rk = deg[t]; }   // self-loop occupies the last slot
    unsigned int rec = (unsigned int)(s & 0xFFFF) |
                       ((unsigned int)f2bf(dinv[s] * dinv[t]) << 16);
    csr[rowptr[t] + rk] = rec;
}

// ---- MFMA GEMM body (R7/R9/R11 verbatim: bf16 output). BF16IN=true computes normp inline. ----
template <bool BF16IN>
__device__ __forceinline__ void gemm_body(int bid, const void* __restrict__ Ain,
                                          const unsigned short* __restrict__ Wsw,
                                          const float* __restrict__ bnp2,
                                          const float* __restrict__ gg,
                                          const float* __restrict__ bb,
                                          unsigned short* __restrict__ C) {
    __shared__ unsigned short Atile[64 * 128];  // 16 KB, swizzled 16B chunks
    __shared__ float rep[4][16][68];            // 17.4 KB, per-wave repack
    __shared__ float normp[256];                // 1 KB scale/shift
    int tid = threadIdx.x;
    int wslot = tid >> 6;
    int l = tid & 63;
    int m = l & 15;
    int q = l >> 4;
    int rblk = bid * 64;

    if (BF16IN) {
        float tot = 0.f;
#pragma unroll 8
        for (int r = 0; r < RED1; r++) tot += bnp2[(size_t)r * 256 + tid];
        normp[tid] = tot;
        __syncthreads();
        if (tid < 128) {
            float sm = normp[tid], sq = normp[128 + tid];
            const float invN = 1.0f / (float)NN;
            float mu = sm * invN;
            float var = sq * invN - mu * mu;
            float sc = rsqrtf(var + 1e-5f) * gg[tid];
            normp[tid] = sc;
            normp[128 + tid] = bb[tid] - mu * sc;
        }
        __syncthreads();
    }

#pragma unroll
    for (int p = 0; p < 4; p++) {
        int rowl = p * 16 + (tid >> 4);
        int c = tid & 15;
        int row = min(rblk + rowl, NN - 1);
        float a[8];
        if (BF16IN) {
            uint4 u = *(const uint4*)((const unsigned short*)Ain + (size_t)row * DD + c * 8);
            a[0] = bflo(u.x); a[1] = bfhi(u.x); a[2] = bflo(u.y); a[3] = bfhi(u.y);
            a[4] = bflo(u.z); a[5] = bfhi(u.z); a[6] = bflo(u.w); a[7] = bfhi(u.w);
#pragma unroll
            for (int j = 0; j < 8; j++) {
                float v = fmaf(a[j], normp[c * 8 + j], normp[128 + c * 8 + j]);
                a[j] = (v >= 0.f) ? v : 0.01f * v;
            }
        } else {
            const float* Af = (const float*)Ain + (size_t)row * DD + c * 8;
            float4 x0 = *(const float4*)Af;
            float4 x1 = *(const float4*)(Af + 4);
            a[0] = x0.x; a[1] = x0.y; a[2] = x0.z; a[3] = x0.w;
            a[4] = x1.x; a[5] = x1.y; a[6] = x1.z; a[7] = x1.w;
        }
        unsigned int w0 = f2bf(a[0]) | ((unsigned int)f2bf(a[1]) << 16);
        unsigned int w1 = f2bf(a[2]) | ((unsigned int)f2bf(a[3]) << 16);
        unsigned int w2 = f2bf(a[4]) | ((unsigned int)f2bf(a[5]) << 16);
        unsigned int w3 = f2bf(a[6]) | ((unsigned int)f2bf(a[7]) << 16);
        uint4 wv; wv.x = w0; wv.y = w1; wv.z = w2; wv.w = w3;
        *(uint4*)&Atile[rowl * 128 + ((c ^ (rowl & 15)) * 8)] = wv;
    }
    __syncthreads();

    f32x4 acc[8];
#pragma unroll
    for (int i = 0; i < 8; i++) acc[i] = (f32x4){0.f, 0.f, 0.f, 0.f};
    int rowl_w = wslot * 16 + m;
#pragma unroll
    for (int kc = 0; kc < 4; kc++) {
        short8 af = *(const short8*)&Atile[rowl_w * 128 + (((kc * 4 + q) ^ m) * 8)];
#pragma unroll
        for (int nt = 0; nt < 8; nt++) {
            short8 bf = *(const short8*)(Wsw + ((size_t)(kc * 8 + nt) * 64 + l) * 8);
            acc[nt] = __builtin_amdgcn_mfma_f32_16x16x32_bf16(af, bf, acc[nt], 0, 0, 0);
        }
    }

    int wrow0 = rblk + wslot * 16;
    int r2 = l >> 2, c2 = l & 3;
#pragma unroll
    for (int pass = 0; pass < 2; pass++) {
#pragma unroll
        for (int ntl = 0; ntl < 4; ntl++) {
            f32x4 a = acc[pass * 4 + ntl];
#pragma unroll
            for (int r = 0; r < 4; r++)
                rep[wslot][q * 4 + r][ntl * 16 + m] = a[r];
        }
        const float* tr = &rep[wslot][r2][c2 * 16];
        float4 v0 = *(const float4*)(tr);
        float4 v1 = *(const float4*)(tr + 4);
        float4 v2 = *(const float4*)(tr + 8);
        float4 v3 = *(const float4*)(tr + 12);
        uint4 oA, oB;
        oA.x = f2bf(v0.x) | ((unsigned int)f2bf(v0.y) << 16);
        oA.y = f2bf(v0.z) | ((unsigned int)f2bf(v0.w) << 16);
        oA.z = f2bf(v1.x) | ((unsigned int)f2bf(v1.y) << 16);
        oA.w = f2bf(v1.z) | ((unsigned int)f2bf(v1.w) << 16);
        oB.x = f2bf(v2.x) | ((unsigned int)f2bf(v2.y) << 16);
        oB.y = f2bf(v2.z) | ((unsigned int)f2bf(v2.w) << 16);
        oB.z = f2bf(v3.x) | ((unsigned int)f2bf(v3.y) << 16);
        oB.w = f2bf(v3.z) | ((unsigned int)f2bf(v3.w) << 16);
        int row = wrow0 + r2;
        if (row < NN) {
            unsigned short* cp = C + (size_t)row * DD + pass * 64 + c2 * 16;
            *(uint4*)cp = oA;
            *(uint4*)(cp + 8) = oB;
        }
    }
}

// ---- gemm L0 || fill, INTERLEAVED: each group of 15 bids = 4 gemm + 11 fill ----
__global__ __launch_bounds__(256) void gemmfill_kernel(const float* __restrict__ x,
                                                       const unsigned short* __restrict__ Wsw,
                                                       unsigned short* __restrict__ C,
                                                       const int* __restrict__ src, const int* __restrict__ dst,
                                                       const int* __restrict__ rowptr,
                                                       const int* __restrict__ rank, const int* __restrict__ deg,
                                                       const float* __restrict__ dinv, unsigned int* __restrict__ csr) {
    int bid = blockIdx.x;
    bool isg;
    int id;
    if (bid < GF_FULL) {
        int grp = bid / 15, r = bid % 15;
        if (r < 4) { isg = true;  id = grp * 4 + r; }
        else       { isg = false; id = grp * 11 + (r - 4); }
    } else {
        int j = bid - GF_FULL;
        if (j < 2) { isg = true;  id = GF_G936 + j; }
        else       { isg = false; id = GF_F2574 + (j - 2); }
    }
    if (isg)
        gemm_body<false>(id, x, Wsw, nullptr, nullptr, nullptr, C);
    else
        fill_body(id, src, dst, rowptr, rank, deg, dinv, csr);
}

__global__ __launch_bounds__(256) void gemm_bf16_kernel(const unsigned short* __restrict__ Ain,
                                                        const unsigned short* __restrict__ Wsw,
                                                        const float* __restrict__ bnp2,
                                                        const float* __restrict__ g,
                                                        const float* __restrict__ be,
                                                        unsigned short* __restrict__ C) {
    gemm_body<true>(blockIdx.x, Ain, Wsw, bnp2, g, be, C);
}

// ---- CSR gather: R9/R11 verbatim (quarter-wave, no epilogue, no barrier) ----
__global__ __launch_bounds__(256) void gather_kernel(const unsigned short* __restrict__ xw,
                                                     const int* __restrict__ rowptr,
                                                     const unsigned int* __restrict__ csr,
                                                     unsigned short* __restrict__ agg) {
    int wid = (int)((blockIdx.x * 256 + threadIdx.x) >> 6);
    int l = threadIdx.x & 63;
    if (wid >= NN) return;
    int beg = rowptr[wid], end = rowptr[wid + 1];
    int q = l >> 4;          // quarter-wave: edge slot 0..3
    int fb = (l & 15) * 8;   // first feature of this lane's 16B chunk
    float a0 = 0.f, a1 = 0.f, a2 = 0.f, a3 = 0.f, a4 = 0.f, a5 = 0.f, a6 = 0.f, a7 = 0.f;
    for (int base = beg; base < end; base += 64) {
        int nrec = min(end - base, 64);
        unsigned int myrec = csr[base + min(l, nrec - 1)];  // all records for this chunk, one load
        int i = 0;
        for (; i + 8 <= nrec; i += 8) {
            unsigned int r0 = __shfl(myrec, i + q);
            unsigned int r1 = __shfl(myrec, i + 4 + q);
            uint4 u0 = *(const uint4*)(xw + (size_t)(r0 & 0xFFFFu) * DD + fb);
            uint4 u1 = *(const uint4*)(xw + (size_t)(r1 & 0xFFFFu) * DD + fb);
            float c0 = bfhi(r0), c1 = bfhi(r1);
            a0 += bflo(u0.x) * c0; a1 += bfhi(u0.x) * c0;
            a2 += bflo(u0.y) * c0; a3 += bfhi(u0.y) * c0;
            a4 += bflo(u0.z) * c0; a5 += bfhi(u0.z) * c0;
            a6 += bflo(u0.w) * c0; a7 += bfhi(u0.w) * c0;
            a0 += bflo(u1.x) * c1; a1 += bfhi(u1.x) * c1;
            a2 += bflo(u1.y) * c1; a3 += bfhi(u1.y) * c1;
            a4 += bflo(u1.z) * c1; a5 += bfhi(u1.z) * c1;
            a6 += bflo(u1.w) * c1; a7 += bfhi(u1.w) * c1;
        }
        for (; i < nrec; i += 4) {
            int e = i + q;
            unsigned int r = __shfl(myrec, min(e, nrec - 1));
            float c = (e < nrec) ? bfhi(r) : 0.f;   // dummy lanes hit a hot line, coef 0
            uint4 u = *(const uint4*)(xw + (size_t)(r & 0xFFFFu) * DD + fb);
            a0 += bflo(u.x) * c; a1 += bfhi(u.x) * c;
            a2 += bflo(u.y) * c; a3 += bfhi(u.y) * c;
            a4 += bflo(u.z) * c; a5 += bfhi(u.z) * c;
            a6 += bflo(u.w) * c; a7 += bfhi(u.w) * c;
        }
    }
    a0 += __shfl_xor(a0, 16); a0 += __shfl_xor(a0, 32);
    a1 += __shfl_xor(a1, 16); a1 += __shfl_xor(a1, 32);
    a2 += __shfl_xor(a2, 16); a2 += __shfl_xor(a2, 32);
    a3 += __shfl_xor(a3, 16); a3 += __shfl_xor(a3, 32);
    a4 += __shfl_xor(a4, 16); a4 += __shfl_xor(a4, 32);
    a5 += __shfl_xor(a5, 16); a5 += __shfl_xor(a5, 32);
    a6 += __shfl_xor(a6, 16); a6 += __shfl_xor(a6, 32);
    a7 += __shfl_xor(a7, 16); a7 += __shfl_xor(a7, 32);
    if (q == 0) {
        uint4 o;
        o.x = (unsigned int)f2bf(a0) | ((unsigned int)f2bf(a1) << 16);
        o.y = (unsigned int)f2bf(a2) | ((unsigned int)f2bf(a3) << 16);
        o.z = (unsigned int)f2bf(a4) | ((unsigned int)f2bf(a5) << 16);
        o.w = (unsigned int)f2bf(a6) | ((unsigned int)f2bf(a7) << 16);
        *(uint4*)(agg + (size_t)wid * DD + fb) = o;
    }
}

// ---- BN stats stage 1 (baseline verbatim): per-block partials, grid 938 ----
__global__ __launch_bounds__(256) void bnstat1_kernel(const unsigned short* __restrict__ h,
                                                      float* __restrict__ partials) {
    int t = threadIdx.x;
    int rg = t >> 4;       // row group 0..15
    int c  = t & 15;       // feature chunk: features 8c..8c+7
    int rbase = blockIdx.x * 64;
    float s[8], q[8];
#pragma unroll
    for (int j = 0; j < 8; j++) { s[j] = 0.f; q[j] = 0.f; }
#pragma unroll
    for (int p = 0; p < 4; p++) {
        int row = rbase + rg + 16 * p;
        if (row < NN) {
            uint4 u = *(const uint4*)(h + (size_t)row * DD + c * 8);
            float v;
            v = bflo(u.x); s[0] += v; q[0] += v * v;
            v = bfhi(u.x); s[1] += v; q[1] += v * v;
            v = bflo(u.y); s[2] += v; q[2] += v * v;
            v = bfhi(u.y); s[3] += v; q[3] += v * v;
            v = bflo(u.z); s[4] += v; q[4] += v * v;
            v = bfhi(u.z); s[5] += v; q[5] += v * v;
            v = bflo(u.w); s[6] += v; q[6] += v * v;
            v = bfhi(u.w); s[7] += v; q[7] += v * v;
        }
    }
    __shared__ float lds[2][16][128];  // 16 KB
#pragma unroll
    for (int j = 0; j < 8; j++) {
        lds[0][rg][c * 8 + j] = s[j];
        lds[1][rg][c * 8 + j] = q[j];
    }
    __syncthreads();
    int f = t & 127, stat = t >> 7;
    float acc = 0.f;
#pragma unroll
    for (int r = 0; r < 16; r++) acc += lds[stat][r][f];
    partials[(size_t)blockIdx.x * 256 + stat * 128 + f] = acc;  // coalesced 1KB row
}

// ---- BN reduce stage A (baseline verbatim): 32 blocks each sum ~29 of 938 rows ----
__global__ __launch_bounds__(256) void bnredA_kernel(const float* __restrict__ partials,
                                                     float* __restrict__ p2) {
    int t = threadIdx.x;
    int b = blockIdx.x;  // 0..RED1-1
    float acc = 0.f;
#pragma unroll 4
    for (int r = b; r < NBK1; r += RED1)
        acc += partials[(size_t)r * 256 + t];   // coalesced, independent
    p2[(size_t)b * 256 + t] = acc;
}

// ---- final: out = bf16(agg)*scale+shift, inline finalize. Grid 938. ----
__global__ __launch_bounds__(256) void bnapply_kernel(const unsigned short* __restrict__ h,
                                                      const float* __restrict__ bnp2,
                                                      const float* __restrict__ g,
                                                      const float* __restrict__ be,
                                                      float* __restrict__ out) {
    __shared__ float normp[256];
    int t = threadIdx.x;
    float tot = 0.f;
#pragma unroll 8
    for (int r = 0; r < RED1; r++) tot += bnp2[(size_t)r * 256 + t];
    normp[t] = tot;
    __syncthreads();
    if (t < 128) {
        float sm = normp[t], sq = normp[128 + t];
        const float invN = 1.0f / (float)NN;
        float mu = sm * invN;
        float var = sq * invN - mu * mu;
        float sc = rsqrtf(var + 1e-5f) * g[t];
        normp[t] = sc;
        normp[128 + t] = be[t] - mu * sc;
    }
    __syncthreads();
#pragma unroll
    for (int k = 0; k < 8; k++) {
        int idx = blockIdx.x * 2048 + k * 256 + t;
        if (idx < NN * DD / 4) {
            int d = (idx * 4) & 127;
            uint2 u = *(const uint2*)(h + (size_t)idx * 4);
            float4 sc = *(const float4*)&normp[d];
            float4 sh = *(const float4*)&normp[128 + d];
            float4 o;
            o.x = fmaf(bflo(u.x), sc.x, sh.x);
            o.y = fmaf(bfhi(u.x), sc.y, sh.y);
            o.z = fmaf(bflo(u.y), sc.z, sh.z);
            o.w = fmaf(bfhi(u.y), sc.w, sh.w);
            *(float4*)&out[(size_t)idx * 4] = o;
        }
    }
}

extern "C" void kernel_launch(void* const* d_in, const int* in_sizes, int n_in,
                              void* d_out, int out_size, void* d_ws, size_t ws_size,
                              hipStream_t stream) {
    const float* x = (const float*)d_in[0];
    const int* ei = (const int*)d_in[1];
    const int* srcp = ei;
    const int* dstp = ei + NE;
    const float* w[3]  = {(const float*)d_in[2], (const float*)d_in[6],  (const float*)d_in[10]};
    const float* g[3]  = {(const float*)d_in[4], (const float*)d_in[8],  (const float*)d_in[12]};
    const float* be[3] = {(const float*)d_in[5], (const float*)d_in[9],  (const float*)d_in[13]};

    // workspace layout (~41 MB of 256 MB), all chunks 16-B aligned
    unsigned short* xwb  = (unsigned short*)d_ws;        // bf16 xw  [NN*DD]
    unsigned short* aggb = xwb + (size_t)NN * DD;        // bf16 agg [NN*DD]
    // ---- zeroed region (single memset): deg ----
    int* deg    = (int*)(aggb + (size_t)NN * DD);        // [NN]
    // ---- end zeroed region ----
    int* rowptr = deg + NN;                              // [NN+16]
    float* dinv = (float*)(rowptr + NN + 16);            // [NN]
    int* spart  = (int*)(dinv + NN);                     // [256] scan partials
    float* bnp  = (float*)(spart + 256);                 // [NBK1*256] bn partials (~960 KB)
    float* bnp2 = bnp + (size_t)NBK1 * 256;              // [RED1*256] raw sums
    unsigned short* Wsw = (unsigned short*)(bnp2 + RED1 * 256);  // [3*128*128] bf16
    unsigned int* csr = (unsigned int*)(Wsw + 3 * DD * DD);      // [NTOT] packed {coef_bf16|src16}
    int* rank = (int*)(csr + NTOT);                      // [NE] edge ranks (build phase)
    float* out = (float*)d_out;

    // ---- build: deg+rank||wcvt -> scanA -> scanC(w/ inlined scanB) -> (gemm L0 || fill) ----
    hipMemsetAsync(deg, 0, (size_t)NN * sizeof(int), stream);
    degw_kernel<<<DEGB + 24, 256, 0, stream>>>(dstp, deg, rank, w[0], w[1], w[2], Wsw);
    scanA_kernel<<<NB, 256, 0, stream>>>(deg, spart, dinv);
    scanC_kernel<<<NB, 256, 0, stream>>>(deg, spart, rowptr);
    gemmfill_kernel<<<GF_TOT, 256, 0, stream>>>(x, Wsw, xwb, srcp, dstp, rowptr, rank, deg, dinv, csr);

    for (int L = 0; L < 3; ++L) {
        if (L > 0)
            gemm_bf16_kernel<<<NBK1, 256, 0, stream>>>(aggb, Wsw + (size_t)L * DD * DD,
                                                       bnp2, g[L - 1], be[L - 1], xwb);
        gather_kernel<<<GGRID, 256, 0, stream>>>(xwb, rowptr, csr, aggb);
        bnstat1_kernel<<<NBK1, 256, 0, stream>>>(aggb, bnp);
        bnredA_kernel<<<RED1, 256, 0, stream>>>(bnp, bnp2);
    }
    bnapply_kernel<<<NBK1, 256, 0, stream>>>(aggb, bnp2, g[2], be[2], out);
}